// Round 8
// baseline (390.872 us; speedup 1.0000x reference)
//
#include <hip/hip_runtime.h>
#include <stdint.h>

#define S_LEN 2048
#define BATCH 2
#define DMODEL 1024
#define NHEAD 16
#define DHEAD 64
#define HS ((size_t)S_LEN * DHEAD)   // 131072 elements per (b,h) slice

typedef float floatx4 __attribute__((ext_vector_type(4)));
typedef __bf16 bf16x8 __attribute__((ext_vector_type(8)));

typedef __attribute__((address_space(1))) const uint32_t gas_u32;
typedef __attribute__((address_space(3))) uint32_t las_u32;
// async global->LDS direct copy, 16B per lane; LDS dest = base + lane*16
__device__ __forceinline__ void gld_lds16(const uint16_t* g, uint16_t* l) {
  __builtin_amdgcn_global_load_lds((gas_u32*)g, (las_u32*)l, 16, 0, 0);
}

__device__ __forceinline__ float bf2f(uint16_t u) {
  union { uint32_t i; float f; } x; x.i = ((uint32_t)u) << 16; return x.f;
}
__device__ __forceinline__ uint16_t f2bf(float f) {
  union { float f; uint32_t i; } x; x.f = f;
  uint32_t r = x.i + 0x7fffu + ((x.i >> 16) & 1u);
  return (uint16_t)(r >> 16);
}
// native HW convert (RTNE) — use in hot paths
__device__ __forceinline__ uint16_t f2bf_hw(float f) {
  __bf16 h = (__bf16)f;
  union { __bf16 h; uint16_t u; } c; c.h = h; return c.u;
}
// dual-dtype load of 8 consecutive elements (idx must be 8-aligned) -> bf16x8 pack
__device__ __forceinline__ uint4 ld8(const void* p, size_t idx, int isf32) {
  if (isf32) {
    const float* f = (const float*)p + idx;
    float4 a = *(const float4*)f;
    float4 b = *(const float4*)(f + 4);
    uint4 r; uint16_t* rp = (uint16_t*)&r;
    rp[0] = f2bf(a.x); rp[1] = f2bf(a.y); rp[2] = f2bf(a.z); rp[3] = f2bf(a.w);
    rp[4] = f2bf(b.x); rp[5] = f2bf(b.y); rp[6] = f2bf(b.z); rp[7] = f2bf(b.w);
    return r;
  }
  return *(const uint4*)((const uint16_t*)p + idx);
}
__device__ __forceinline__ float ld1(const void* p, size_t idx, int isf32) {
  return isf32 ? ((const float*)p)[idx] : bf2f(((const uint16_t*)p)[idx]);
}
__device__ __forceinline__ uint4 addb8(uint4 a, uint4 b) {
  uint4 r;
  const uint16_t* pa = (const uint16_t*)&a;
  const uint16_t* pb = (const uint16_t*)&b;
  uint16_t* pr = (uint16_t*)&r;
#pragma unroll
  for (int e = 0; e < 8; e++) pr[e] = f2bf(bf2f(pa[e]) + bf2f(pb[e]));
  return r;
}

// ---------------------------------------------------------------------------
// Detect input dtype from x's first 256 u16 words. f32 data: even words are
// uniform random bits -> many decode as |bf16| > 256. bf16 N(0,1) data: none.
__global__ __launch_bounds__(256) void detect_dtype(const void* __restrict__ x,
                                                    int* __restrict__ flag) {
  __shared__ int cnt;
  if (threadIdx.x == 0) cnt = 0;
  __syncthreads();
  const uint16_t w = ((const uint16_t*)x)[threadIdx.x];
  const float v = bf2f(w);
  const float av = fabsf(v);
  if (!(av <= 256.f)) atomicAdd(&cnt, 1);  // catches big, Inf, NaN
  __syncthreads();
  if (threadIdx.x == 0) *flag = (cnt >= 8) ? 1 : 0;
}

// ---------------------------------------------------------------------------
// cvt_x: x [S][B][D] (f32 or bf16) -> xb [B][S][D] bf16 (b-split for GEMM A).
__global__ __launch_bounds__(256) void cvt_x(const void* __restrict__ x,
                                             uint16_t* __restrict__ xb,
                                             const int* __restrict__ pflag) {
  const int isf32 = *pflag;
  const size_t gid = (size_t)blockIdx.x * 256 + threadIdx.x;  // S*B*D/8 total
  const int d0 = (int)(gid & (DMODEL / 8 - 1)) * 8;
  const size_t sb = gid >> 7;              // s*B + b
  const size_t s = sb >> 1, b = sb & 1;
  uint4 v = ld8(x, sb * DMODEL + d0, isf32);
  *(uint4*)&xb[(b * S_LEN + s) * DMODEL + d0] = v;
}

// cvt_mat: flat convert src -> dst bf16 (8 elems/thread).
__global__ __launch_bounds__(256) void cvt_mat(const void* __restrict__ src,
                                               uint16_t* __restrict__ dst,
                                               const int* __restrict__ pflag) {
  const int isf32 = *pflag;
  const size_t gid = ((size_t)blockIdx.x * 256 + threadIdx.x) * 8;
  *(uint4*)&dst[gid] = ld8(src, gid, isf32);
}

// cvt_matT: src [R][C] (f32/bf16 row-major) -> dst [C][R] bf16 (transposed).
// One-time weight transpose so GEMM B-staging is pure vector traffic.
__global__ __launch_bounds__(256) void cvt_matT(const void* __restrict__ src,
                                                uint16_t* __restrict__ dst,
                                                int R, int C,
                                                const int* __restrict__ pflag) {
  __shared__ uint16_t lT[64 * 72];
  const int isf32 = *pflag;
  const int tid = threadIdx.x;
  const int c0 = blockIdx.x * 64;
  const int r0 = blockIdx.y * 64;
  {
    const int rr = tid >> 2, cc = (tid & 3) * 16;
    *(uint4*)&lT[rr * 72 + cc]     = ld8(src, (size_t)(r0 + rr) * C + c0 + cc, isf32);
    *(uint4*)&lT[rr * 72 + cc + 8] = ld8(src, (size_t)(r0 + rr) * C + c0 + cc + 8, isf32);
  }
  __syncthreads();
  const int oc = tid >> 2, rc = (tid & 3) * 16;
  uint16_t tmp[16];
#pragma unroll
  for (int e = 0; e < 16; e++) tmp[e] = lT[(rc + e) * 72 + oc];
  uint16_t* dp = dst + (size_t)(c0 + oc) * R + r0 + rc;
  *(uint4*)dp = *(const uint4*)&tmp[0];
  *(uint4*)(dp + 8) = *(const uint4*)&tmp[8];
}

// ---------------------------------------------------------------------------
// qkv_gemm: unified 128x128-tile GEMM for q/k/v/r production.
// grid.x = strip {0,1,2 = q,k,v ; 3 = r}; grid.y = s-block; grid.z = zpair t.
// R7: A staged via global_load_lds width=16 (lA layout [128][32] is linear in
// lane order: lane i of wave w -> offset (w*64+i)*16B). B stays vector-staged
// (40-pad needed for conflict-free reads; glds needs linear dest).
__global__ __launch_bounds__(256) void qkv_gemm(
    const uint16_t* __restrict__ xb, const uint16_t* __restrict__ peb,
    const uint16_t* __restrict__ wqT, const uint16_t* __restrict__ wrT,
    uint16_t* __restrict__ qb, uint16_t* __restrict__ kb,
    uint16_t* __restrict__ vb, uint16_t* __restrict__ rb, int z0) {
  __shared__ uint16_t lA[128 * 32];
  __shared__ uint16_t lB[128 * 40];
  const int tid = threadIdx.x;
  const int lane = tid & 63;
  const int wave = tid >> 6;
  const int wm = wave >> 1, wn = wave & 1;
  const int strip = blockIdx.x;
  const int zg0 = z0 + 2 * blockIdx.z;
  const int b = zg0 >> 4, h0 = zg0 & 15;

  const uint16_t* Ab;
  const uint16_t* BT;
  int col0;
  if (strip < 3) {
    Ab = xb + (size_t)b * S_LEN * DMODEL;
    BT = wqT; col0 = strip * DMODEL + h0 * 64;
  } else {
    Ab = peb;
    BT = wrT; col0 = h0 * 64;
  }
  Ab += (size_t)blockIdx.y * 128 * DMODEL;

  floatx4 acc[4][4];
  floatx4 zero4 = {0.f, 0.f, 0.f, 0.f};
#pragma unroll
  for (int i = 0; i < 4; i++)
#pragma unroll
    for (int j = 0; j < 4; j++) acc[i][j] = zero4;

  const int arow = tid >> 2;
  const int kcol = (tid & 3) * 8;
  const int brow = tid >> 1;        // 0..127 (B n-row)
  const int bkc = (tid & 1) * 16;   // 0 / 16

  for (int k0 = 0; k0 < DMODEL; k0 += 32) {
    // A: async global->LDS, 16B/lane; wave-uniform LDS base
    gld_lds16(Ab + (size_t)arow * DMODEL + k0 + kcol, &lA[wave * 512]);
    gld_lds16(Ab + (size_t)(64 + arow) * DMODEL + k0 + kcol, &lA[2048 + wave * 512]);
    const uint16_t* bp = BT + (size_t)(col0 + brow) * DMODEL + k0 + bkc;
    *(uint4*)&lB[brow * 40 + bkc]     = *(const uint4*)bp;
    *(uint4*)&lB[brow * 40 + bkc + 8] = *(const uint4*)(bp + 8);
    __syncthreads();
    bf16x8 af[4], bfr[4];
#pragma unroll
    for (int mi = 0; mi < 4; mi++)
      af[mi] = *(const bf16x8*)&lA[(wm * 64 + mi * 16 + (lane & 15)) * 32 + (lane >> 4) * 8];
#pragma unroll
    for (int ni = 0; ni < 4; ni++)
      bfr[ni] = *(const bf16x8*)&lB[(wn * 64 + ni * 16 + (lane & 15)) * 40 + (lane >> 4) * 8];
#pragma unroll
    for (int mi = 0; mi < 4; mi++)
#pragma unroll
      for (int ni = 0; ni < 4; ni++)
        acc[mi][ni] = __builtin_amdgcn_mfma_f32_16x16x32_bf16(af[mi], bfr[ni], acc[mi][ni], 0, 0, 0);
    __syncthreads();
  }

  uint16_t* ob = (strip == 0) ? qb : (strip == 1) ? kb : (strip == 2) ? vb : rb;
  const int r0 = blockIdx.y * 128 + wm * 64;
  const int zlb = 2 * blockIdx.z;
#pragma unroll
  for (int mi = 0; mi < 4; mi++)
#pragma unroll
    for (int ni = 0; ni < 4; ni++)
#pragma unroll
      for (int v = 0; v < 4; v++) {
        const int sg = r0 + mi * 16 + (lane >> 4) * 4 + v;
        const int c  = wn * 64 + ni * 16 + (lane & 15);
        const int zl = zlb + (c >> 6);
        const int d  = c & 63;
        ob[(size_t)zl * HS + (size_t)sg * 64 + d] = f2bf_hw(acc[mi][ni][v]);
      }
}

// ---------------------------------------------------------------------------
// transpose_v: vb [2048][64] per z -> vt [64][2048] per z.
__global__ __launch_bounds__(256) void transpose_v(const uint16_t* __restrict__ vb,
                                                   uint16_t* __restrict__ vt) {
  __shared__ uint16_t lT[64 * 72];
  const int tid = threadIdx.x;
  const int zl = blockIdx.y;
  const int j0 = blockIdx.x * 64;
  const uint16_t* src = vb + (size_t)zl * HS + (size_t)j0 * 64;
  {
    const int j = tid >> 2, dc = (tid & 3) * 16;
    *(uint4*)&lT[j * 72 + dc] = *(const uint4*)(src + (size_t)j * 64 + dc);
    *(uint4*)&lT[j * 72 + dc + 8] = *(const uint4*)(src + (size_t)j * 64 + dc + 8);
  }
  __syncthreads();
  const int d = tid >> 2, jc = (tid & 3) * 16;
  uint16_t tmp[16];
#pragma unroll
  for (int e = 0; e < 16; e++) tmp[e] = lT[(jc + e) * 72 + d];
  uint16_t* dst = vt + (size_t)zl * HS + (size_t)d * S_LEN + j0 + jc;
  *(uint4*)dst = *(const uint4*)&tmp[0];
  *(uint4*)(dst + 8) = *(const uint4*)&tmp[8];
}

// ---------------------------------------------------------------------------
// flash_attn: fused AC + rel-shifted BD + online softmax + PV.
//
// rel-shift: D = j - i; BD[i][j] = (D<=0) ? (q_i+bv).r[D+S-1]
//                       : (D==1) ? 0 : (q_{i+1}+bv).r[D-2]
// r band STAGED in LDS (coalesced). Shear applied IN REGISTERS via lane
// rotation: src lane = l4*16 + ((l15+15-r)&15), fragment f' = f + (l15>r).
//
// 1 BLOCK/CU (launch_bounds(512,2), ~106 KB LDS): co-resident blocks sweep
// bx in LOCKSTEP -> cache reuse works (FETCH 16.5 MB). Do not raise blk/CU.
// T14 async-STAGE via explicit register vars (R6, verified no spill).
// R7: softmax in exp2 domain (0.125*log2e folded into combine scale) and
// PBP=132 (66 dwords/row: 4-row stride = 8 mod 32 -> P-write l4-groups hit
// disjoint bank octets; was 4-way at PBP=136).
#define FBP 72    // K-tile & r-band LDS row stride (elems)
#define VTP 136   // V^T tile LDS row stride
#define PBP 132   // softmaxed-P LDS row stride (bank-conflict-free writes)
#define SC2 0.180336880f  // 0.125 * log2(e)

#define FA_ISSUE(bxn) do {                                                  \
    const uint16_t* spk_ = kz + (size_t)((bxn) * 128 + sj) * 64 + skc;      \
    kr0 = *(const uint4*)spk_;                                              \
    kr1 = *(const uint4*)(spk_ + 8);                                        \
    const uint16_t* spv_ = vz + (size_t)sd * S_LEN + (bxn) * 128 + sjc;     \
    vr0 = *(const uint4*)spv_;                                              \
    vr1 = *(const uint4*)(spv_ + 8);                                        \
    const int Dq_ = ((bxn) - by) * 128 + sslot - 127;                       \
    int rrow_ = (Dq_ <= 0) ? (Dq_ + S_LEN - 1) : (Dq_ - 2 < 0 ? 0 : Dq_ - 2); \
    if (rrow_ > S_LEN - 1) rrow_ = S_LEN - 1;                               \
    const uint16_t* spr_ = rz + (size_t)rrow_ * 64 + shalf;                 \
    br0 = *(const uint4*)spr_;                                              \
    br1 = *(const uint4*)(spr_ + 8);                                        \
    br2 = *(const uint4*)(spr_ + 16);                                       \
    br3 = *(const uint4*)(spr_ + 24);                                       \
  } while (0)

#define FA_COMMIT() do {                                                    \
    *(uint4*)&lK[sj * FBP + skc]     = kr0;                                 \
    *(uint4*)&lK[sj * FBP + skc + 8] = kr1;                                 \
    *(uint4*)&lV[sd * VTP + sjc]     = vr0;                                 \
    *(uint4*)&lV[sd * VTP + sjc + 8] = vr1;                                 \
    uint16_t* dp_ = &lR[sslot * FBP + shalf];                               \
    *(uint4*)(dp_)      = br0;                                              \
    *(uint4*)(dp_ + 8)  = br1;                                              \
    *(uint4*)(dp_ + 16) = br2;                                              \
    *(uint4*)(dp_ + 24) = br3;                                              \
  } while (0)

__global__ __launch_bounds__(512, 2) void flash_attn(
    const uint16_t* __restrict__ qb, const uint16_t* __restrict__ kb,
    const uint16_t* __restrict__ vt, const uint16_t* __restrict__ rb,
    const void* __restrict__ bu, const void* __restrict__ bv,
    uint16_t* __restrict__ avec, int z0, int zc,
    const int* __restrict__ pflag) {
  __shared__ uint16_t lK[128 * FBP];     // K tile [128][64]
  __shared__ uint16_t lV[64 * VTP];      // V^T tile [64][128]
  __shared__ uint16_t lR[256 * FBP];     // r band [256][64]
  __shared__ uint16_t lP[8 * 16 * PBP];  // per-wave softmaxed P
  const int isf32 = *pflag;
  const int tid = threadIdx.x;
  const int lane = tid & 63;
  const int w = tid >> 6;            // wave 0..7, owns 16 output rows
  const int l15 = lane & 15;
  const int l4 = lane >> 4;
  // XCD-pinned decode (round-robin bid%8 -> XCD): all 16 by-blocks of a zl
  // land on one XCD; cohort of 256 resident blocks = 2 zl per XCD.
  int by, zl;
  {
    const int bid = blockIdx.x;
    if ((zc & 7) == 0) {
      const int xcd = bid & 7;
      const int t = bid >> 3;
      by = t & 15;
      zl = xcd + 8 * (t >> 4);
    } else {
      by = bid & 15;
      zl = bid >> 4;
    }
  }
  const int zg = z0 + zl;
  const int b = zg >> 4, h = zg & 15;
  const int i0 = by * 128;

  const uint16_t* qz = qb + (size_t)zl * HS;
  const uint16_t* kz = kb + (size_t)zl * HS;
  const uint16_t* vz = vt + (size_t)zl * HS;
  const uint16_t* rz = rb + (size_t)zl * HS;
  uint16_t* pbw = lP + w * 16 * PBP;        // wave-local P slice
  const int cmin = 112 - 16 * w;     // wave's band window start (abs band col)
  const int r_loc = l4 * 4;

  // staging thread roles (fixed per thread)
  const int sj = tid >> 2, skc = (tid & 3) * 16;      // K
  const int sd = tid >> 3, sjc = (tid & 7) * 16;      // V^T
  const int sslot = tid >> 1, shalf = (tid & 1) * 32; // band

  // staged register tiles (explicit top-level vars; no lambda captures)
  uint4 kr0, kr1, vr0, vr1, br0, br1, br2, br3;

  // Preload A fragments: af1 = q+bu (AC), af2 = q+bv, af2s = q_{row+1}+bv.
  uint4 af1[2], af2[2], af2s[2];
  {
    const int qrow = i0 + w * 16 + l15;
    const int qrow1 = min(qrow + 1, S_LEN - 1);  // clamped row never consumed
#pragma unroll
    for (int ks = 0; ks < 2; ks++) {
      const int kc = ks * 32 + l4 * 8;
      uint4 bub = ld8(bu, (size_t)h * 64 + kc, isf32);
      uint4 bvb = ld8(bv, (size_t)h * 64 + kc, isf32);
      uint4 qv  = *(const uint4*)(qz + (size_t)qrow * 64 + kc);
      uint4 qv1 = *(const uint4*)(qz + (size_t)qrow1 * 64 + kc);
      af1[ks]  = addb8(qv, bub);
      af2[ks]  = addb8(qv, bvb);
      af2s[ks] = addb8(qv1, bvb);
    }
  }

  floatx4 acc_o[4];
  floatx4 zero4 = {0.f, 0.f, 0.f, 0.f};
#pragma unroll
  for (int i = 0; i < 4; i++) acc_o[i] = zero4;
  float m[4] = {-1e30f, -1e30f, -1e30f, -1e30f};
  float l[4] = {0.f, 0.f, 0.f, 0.f};

  // prologue: stage tile 0
  FA_ISSUE(0);
  FA_COMMIT();
  __syncthreads();

  for (int bx = 0; bx < 16; ++bx) {
    const int del = bx - by;
    // T14: issue next tile's loads now; they retire under the compute below
    if (bx < 15) FA_ISSUE(bx + 1);

    // band GEMM: 9 fragments covering wave's 144-wide window (B from lR)
    floatx4 accp[9];
#pragma unroll
    for (int f = 0; f < 9; f++) accp[f] = zero4;
#pragma unroll
    for (int ks = 0; ks < 2; ks++) {
      const bf16x8 a1 = *(const bf16x8*)&af2[ks];
      const bf16x8 a2 = *(const bf16x8*)&af2s[ks];
#pragma unroll
      for (int f = 0; f < 9; f++) {
        const int cb = cmin + 16 * f;
        const bf16x8 brg = *(const bf16x8*)&lR[(cb + l15) * FBP + ks * 32 + l4 * 8];
        const bf16x8 a = (cb >= 128 - 128 * del) ? a2 : a1;  // wave-uniform
        accp[f] = __builtin_amdgcn_mfma_f32_16x16x32_bf16(a, brg, accp[f], 0, 0, 0);
      }
    }
    // AC GEMM: S_ac[16 rows][128 cols] per wave
    floatx4 acc_s[8];
#pragma unroll
    for (int f = 0; f < 8; f++) acc_s[f] = zero4;
#pragma unroll
    for (int ks = 0; ks < 2; ks++) {
      const bf16x8 a = *(const bf16x8*)&af1[ks];
#pragma unroll
      for (int f = 0; f < 8; f++) {
        const bf16x8 bk = *(const bf16x8*)&lK[(f * 16 + l15) * FBP + ks * 32 + l4 * 8];
        acc_s[f] = __builtin_amdgcn_mfma_f32_16x16x32_bf16(a, bk, acc_s[f], 0, 0, 0);
      }
    }

    // in-register shear + combine + scale (exp2 domain) + rowmax
    float rmax[4] = {-1e30f, -1e30f, -1e30f, -1e30f};
#pragma unroll
    for (int v = 0; v < 4; v++) {
      const int r = r_loc + v;
      const int srcl = l4 * 16 + ((l15 + 15 - r) & 15);
      float sh[9];
#pragma unroll
      for (int f = 0; f < 9; f++) sh[f] = __shfl(accp[f][v], srcl);
      const int Dbase = del * 128 + l15 - w * 16 - r;  // D = Dbase + 16f
#pragma unroll
      for (int f = 0; f < 8; f++) {
        float bd = (l15 <= r) ? sh[f] : sh[f + 1];
        if (Dbase + 16 * f == 1) bd = 0.f;
        const float sv = (acc_s[f][v] + bd) * SC2;   // log2-domain score
        acc_s[f][v] = sv;
        rmax[v] = fmaxf(rmax[v], sv);
      }
    }
    // online softmax (all exps are 2^x -> single v_exp_f32)
#pragma unroll
    for (int v = 0; v < 4; v++) {
#pragma unroll
      for (int o = 1; o < 16; o <<= 1) rmax[v] = fmaxf(rmax[v], __shfl_xor(rmax[v], o));
      const float mn = fmaxf(m[v], rmax[v]);
      const float al = __builtin_amdgcn_exp2f(m[v] - mn);
      m[v] = mn;
      l[v] *= al;
#pragma unroll
      for (int nd = 0; nd < 4; nd++) acc_o[nd][v] *= al;
    }
    float rsum[4] = {0.f, 0.f, 0.f, 0.f};
#pragma unroll
    for (int f = 0; f < 8; f++)
#pragma unroll
      for (int v = 0; v < 4; v++) {
        const float p = __builtin_amdgcn_exp2f(acc_s[f][v] - m[v]);
        acc_s[f][v] = p;
        rsum[v] += p;
      }
#pragma unroll
    for (int v = 0; v < 4; v++) {
#pragma unroll
      for (int o = 1; o < 16; o <<= 1) rsum[v] += __shfl_xor(rsum[v], o);
      l[v] += rsum[v];
    }
    // write softmaxed P [16][128] into wave-local lP (separate buffer ->
    // no cross-wave hazard, no barrier)
#pragma unroll
    for (int f = 0; f < 8; f++)
#pragma unroll
      for (int v = 0; v < 4; v++)
        pbw[(r_loc + v) * PBP + f * 16 + l15] = f2bf_hw(acc_s[f][v]);

    // PV GEMM: acc_o += P(16x128) . V(128x64)
#pragma unroll
    for (int ks = 0; ks < 4; ks++) {
      const bf16x8 ap = *(const bf16x8*)&pbw[l15 * PBP + ks * 32 + l4 * 8];
#pragma unroll
      for (int nd = 0; nd < 4; nd++) {
        const bf16x8 bvv = *(const bf16x8*)&lV[(nd * 16 + l15) * VTP + ks * 32 + l4 * 8];
        acc_o[nd] = __builtin_amdgcn_mfma_f32_16x16x32_bf16(ap, bvv, acc_o[nd], 0, 0, 0);
      }
    }

    __syncthreads();  // (A) all waves' lK/lV/lR reads of tile bx done
    if (bx < 15) {
      FA_COMMIT();     // staged regs -> LDS (loads already retired)
      __syncthreads(); // (B) tile bx+1 visible
    }
  }

  // epilogue: normalize by row sum, write avec
#pragma unroll
  for (int v = 0; v < 4; v++) {
    const float inv = 1.f / l[v];
    const int i = i0 + w * 16 + r_loc + v;
#pragma unroll
    for (int nd = 0; nd < 4; nd++) {
      const int d = nd * 16 + l15;
      avec[((size_t)i * BATCH + b) * DMODEL + h * 64 + d] = f2bf_hw(acc_o[nd][v] * inv);
    }
  }
}

// ---------------------------------------------------------------------------
// out_gemm: ybuf = avec (4096x1024) @ Wo (via pre-transposed woT [n][k]) + x.
// R7: A staged via global_load_lds width=16 (same linear layout as qkv_gemm).
__global__ __launch_bounds__(256) void out_gemm(
    const uint16_t* __restrict__ avec, const uint16_t* __restrict__ woT,
    const void* __restrict__ x, uint16_t* __restrict__ ybuf,
    const int* __restrict__ pflag) {
  __shared__ uint16_t lA[128 * 32];
  __shared__ uint16_t lB[128 * 40];
  const int isf32 = *pflag;
  const int tid = threadIdx.x;
  const int lane = tid & 63;
  const int wave = tid >> 6;
  const int wm = wave >> 1, wn = wave & 1;
  const uint16_t* Ab = avec + (size_t)blockIdx.y * 128 * DMODEL;
  const int col0 = blockIdx.x * 128;

  floatx4 acc[4][4];
  floatx4 zero4 = {0.f, 0.f, 0.f, 0.f};
#pragma unroll
  for (int i = 0; i < 4; i++)
#pragma unroll
    for (int j = 0; j < 4; j++) acc[i][j] = zero4;

  const int arow = tid >> 2;
  const int kcol = (tid & 3) * 8;
  const int brow = tid >> 1;        // 0..127
  const int bkc = (tid & 1) * 16;   // 0 / 16

  for (int k0 = 0; k0 < DMODEL; k0 += 32) {
    gld_lds16(Ab + (size_t)arow * DMODEL + k0 + kcol, &lA[wave * 512]);
    gld_lds16(Ab + (size_t)(64 + arow) * DMODEL + k0 + kcol, &lA[2048 + wave * 512]);
    const uint16_t* bp = woT + (size_t)(col0 + brow) * DMODEL + k0 + bkc;
    *(uint4*)&lB[brow * 40 + bkc]     = *(const uint4*)bp;
    *(uint4*)&lB[brow * 40 + bkc + 8] = *(const uint4*)(bp + 8);
    __syncthreads();
    bf16x8 af[4], bfr[4];
#pragma unroll
    for (int mi = 0; mi < 4; mi++)
      af[mi] = *(const bf16x8*)&lA[(wm * 64 + mi * 16 + (lane & 15)) * 32 + (lane >> 4) * 8];
#pragma unroll
    for (int ni = 0; ni < 4; ni++)
      bfr[ni] = *(const bf16x8*)&lB[(wn * 64 + ni * 16 + (lane & 15)) * 40 + (lane >> 4) * 8];
#pragma unroll
    for (int mi = 0; mi < 4; mi++)
#pragma unroll
      for (int ni = 0; ni < 4; ni++)
        acc[mi][ni] = __builtin_amdgcn_mfma_f32_16x16x32_bf16(af[mi], bfr[ni], acc[mi][ni], 0, 0, 0);
    __syncthreads();
  }

  const int r0 = blockIdx.y * 128 + wm * 64;
#pragma unroll
  for (int mi = 0; mi < 4; mi++)
#pragma unroll
    for (int ni = 0; ni < 4; ni++)
#pragma unroll
      for (int v = 0; v < 4; v++) {
        const int rg = r0 + mi * 16 + (lane >> 4) * 4 + v;
        const int cg = col0 + wn * 64 + ni * 16 + (lane & 15);
        const size_t o = (size_t)rg * DMODEL + cg;
        ybuf[o] = f2bf_hw(acc[mi][ni][v] + ld1(x, o, isf32));
      }
}

// ---------------------------------------------------------------------------
// LayerNorm over D=1024, bf16 in (ybuf), FLOAT32 out (reference output dtype).
__global__ __launch_bounds__(256) void ln_f32(
    const uint16_t* __restrict__ y, const void* __restrict__ gamma,
    const void* __restrict__ beta, float* __restrict__ out,
    const int* __restrict__ pflag) {
  const int isf32 = *pflag;
  const int row = blockIdx.x;
  const int tid = threadIdx.x;
  const int lane = tid & 63, wave = tid >> 6;
  const uint16_t* yr = y + (size_t)row * DMODEL;
  uint2 u = *(const uint2*)(yr + tid * 4);
  const uint16_t* up = (const uint16_t*)&u;
  float f[4];
  float s = 0.f, q = 0.f;
#pragma unroll
  for (int j = 0; j < 4; j++) { f[j] = bf2f(up[j]); s += f[j]; q += f[j] * f[j]; }
#pragma unroll
  for (int o = 32; o; o >>= 1) { s += __shfl_xor(s, o); q += __shfl_xor(q, o); }
  __shared__ float rs[4], rq[4];
  if (lane == 0) { rs[wave] = s; rq[wave] = q; }
  __syncthreads();
  s = rs[0] + rs[1] + rs[2] + rs[3];
  q = rq[0] + rq[1] + rq[2] + rq[3];
  const float mu = s * (1.f / DMODEL);
  const float var = fmaxf(q * (1.f / DMODEL) - mu * mu, 0.f);
  const float inv = rsqrtf(var + 1e-5f);
  float4 o4;
  float* op = (float*)&o4;
#pragma unroll
  for (int j = 0; j < 4; j++) {
    const int c = tid * 4 + j;
    float r = (f[j] - mu) * inv * ld1(gamma, c, isf32) + ld1(beta, c, isf32);
    if (!(r == r)) r = 1e4f;  // diagnostic sentinel: NaN reached LN
    op[j] = r;
  }
  *(float4*)(out + (size_t)row * DMODEL + tid * 4) = o4;
}

// Sentinel: ws too small — fill output with 1e6 so absmax reports it.
__global__ __launch_bounds__(256) void sentinel_fill(float* __restrict__ out) {
  const size_t i = (size_t)blockIdx.x * 1024 + threadIdx.x * 4;
  out[i] = 1e6f; out[i + 1] = 1e6f; out[i + 2] = 1e6f; out[i + 3] = 1e6f;
}

extern "C" void kernel_launch(void* const* d_in, const int* in_sizes, int n_in,
                              void* d_out, int out_size, void* d_ws, size_t ws_size,
                              hipStream_t stream) {
  const void* x    = d_in[0];
  const void* pe   = d_in[1];
  const void* bu   = d_in[2];
  const void* bv   = d_in[3];
  const void* Wqkv = d_in[4];
  const void* Wrel = d_in[5];
  const void* Wo   = d_in[6];
  const void* gam  = d_in[7];
  const void* bet  = d_in[8];
  float* out = (float*)d_out;

  // Layout: [flag 256B][qb|kb|vb|rb|vt: 5*ZC*256KB]
  //         [conv: xb 8M | peb 4M | wqT 6M | wrT 2M | woT 2M]
  // ybuf (8 MB) reuses xb after attention completes.
  const size_t per_z = 5 * HS * 2;                                   // 1.25 MB
  const size_t conv_bytes = (size_t)(8 + 4 + 6 + 2 + 2) * 1024 * 1024;
  int ZC = 0;
  for (int c = 32; c >= 2; c >>= 1)
    if (256 + (size_t)c * per_z + conv_bytes <= ws_size) { ZC = c; break; }

  const dim3 blk(256);
  if (ZC == 0) {
    sentinel_fill<<<dim3(4096), blk, 0, stream>>>(out);
    return;
  }

  int* flag = (int*)d_ws;
  uint16_t* qb  = (uint16_t*)((char*)d_ws + 256);
  uint16_t* kb  = qb + (size_t)ZC * HS;
  uint16_t* vb  = kb + (size_t)ZC * HS;
  uint16_t* rb  = vb + (size_t)ZC * HS;
  uint16_t* vtb = rb + (size_t)ZC * HS;
  uint16_t* xbuf = vtb + (size_t)ZC * HS;              // conv region start
  uint16_t* peb  = xbuf + (size_t)BATCH * S_LEN * DMODEL;
  uint16_t* wqT  = peb + (size_t)S_LEN * DMODEL;
  uint16_t* wrT  = wqT + (size_t)DMODEL * 3 * DMODEL;
  uint16_t* woT  = wrT + (size_t)DMODEL * DMODEL;
  uint16_t* ybuf = xbuf;              // reused after attention completes
  uint16_t* avec = (uint16_t*)d_out;  // d_out (16 MB) first 8 MB as bf16 scratch

  detect_dtype<<<dim3(1), blk, 0, stream>>>(x, flag);
  cvt_x<<<dim3(2048), blk, 0, stream>>>(x, xbuf, flag);
  cvt_mat<<<dim3(1024), blk, 0, stream>>>(pe, peb, flag);              // 2048x1024
  cvt_matT<<<dim3(48, 16), blk, 0, stream>>>(Wqkv, wqT, DMODEL, 3 * DMODEL, flag);
  cvt_matT<<<dim3(16, 16), blk, 0, stream>>>(Wrel, wrT, DMODEL, DMODEL, flag);
  cvt_matT<<<dim3(16, 16), blk, 0, stream>>>(Wo,   woT, DMODEL, DMODEL, flag);

  for (int z0 = 0; z0 < 32; z0 += ZC) {
    qkv_gemm<<<dim3(4, 16, ZC / 2), blk, 0, stream>>>(xbuf, peb, wqT, wrT,
                                                      qb, kb, vb, rb, z0);
    transpose_v<<<dim3(32, ZC), blk, 0, stream>>>(vb, vtb);
    flash_attn<<<dim3(16 * ZC), dim3(512), 0, stream>>>(qb, kb, vtb, rb, bu, bv,
                                                        avec, z0, ZC, flag);
  }

  out_gemm<<<dim3(8, 32, 1), blk, 0, stream>>>(avec, woT, x, ybuf, flag);
  ln_f32<<<dim3(4096), blk, 0, stream>>>(ybuf, gam, bet, out, flag);
}

// Round 9
// 361.348 us; speedup vs baseline: 1.0817x; 1.0817x over previous
//
#include <hip/hip_runtime.h>
#include <stdint.h>

#define S_LEN 2048
#define BATCH 2
#define DMODEL 1024
#define NHEAD 16
#define DHEAD 64
#define HS ((size_t)S_LEN * DHEAD)   // 131072 elements per (b,h) slice

typedef float floatx4 __attribute__((ext_vector_type(4)));
typedef __bf16 bf16x8 __attribute__((ext_vector_type(8)));

__device__ __forceinline__ float bf2f(uint16_t u) {
  union { uint32_t i; float f; } x; x.i = ((uint32_t)u) << 16; return x.f;
}
__device__ __forceinline__ uint16_t f2bf(float f) {
  union { float f; uint32_t i; } x; x.f = f;
  uint32_t r = x.i + 0x7fffu + ((x.i >> 16) & 1u);
  return (uint16_t)(r >> 16);
}
// native HW convert (RTNE) — use in hot paths
__device__ __forceinline__ uint16_t f2bf_hw(float f) {
  __bf16 h = (__bf16)f;
  union { __bf16 h; uint16_t u; } c; c.h = h; return c.u;
}
// dual-dtype load of 8 consecutive elements (idx must be 8-aligned) -> bf16x8 pack
__device__ __forceinline__ uint4 ld8(const void* p, size_t idx, int isf32) {
  if (isf32) {
    const float* f = (const float*)p + idx;
    float4 a = *(const float4*)f;
    float4 b = *(const float4*)(f + 4);
    uint4 r; uint16_t* rp = (uint16_t*)&r;
    rp[0] = f2bf(a.x); rp[1] = f2bf(a.y); rp[2] = f2bf(a.z); rp[3] = f2bf(a.w);
    rp[4] = f2bf(b.x); rp[5] = f2bf(b.y); rp[6] = f2bf(b.z); rp[7] = f2bf(b.w);
    return r;
  }
  return *(const uint4*)((const uint16_t*)p + idx);
}
__device__ __forceinline__ float ld1(const void* p, size_t idx, int isf32) {
  return isf32 ? ((const float*)p)[idx] : bf2f(((const uint16_t*)p)[idx]);
}
__device__ __forceinline__ uint4 addb8(uint4 a, uint4 b) {
  uint4 r;
  const uint16_t* pa = (const uint16_t*)&a;
  const uint16_t* pb = (const uint16_t*)&b;
  uint16_t* pr = (uint16_t*)&r;
#pragma unroll
  for (int e = 0; e < 8; e++) pr[e] = f2bf(bf2f(pa[e]) + bf2f(pb[e]));
  return r;
}

// ---------------------------------------------------------------------------
// Detect input dtype from x's first 256 u16 words. f32 data: even words are
// uniform random bits -> many decode as |bf16| > 256. bf16 N(0,1) data: none.
__global__ __launch_bounds__(256) void detect_dtype(const void* __restrict__ x,
                                                    int* __restrict__ flag) {
  __shared__ int cnt;
  if (threadIdx.x == 0) cnt = 0;
  __syncthreads();
  const uint16_t w = ((const uint16_t*)x)[threadIdx.x];
  const float v = bf2f(w);
  const float av = fabsf(v);
  if (!(av <= 256.f)) atomicAdd(&cnt, 1);  // catches big, Inf, NaN
  __syncthreads();
  if (threadIdx.x == 0) *flag = (cnt >= 8) ? 1 : 0;
}

// ---------------------------------------------------------------------------
// cvt_x: x [S][B][D] (f32 or bf16) -> xb [B][S][D] bf16 (b-split for GEMM A).
__global__ __launch_bounds__(256) void cvt_x(const void* __restrict__ x,
                                             uint16_t* __restrict__ xb,
                                             const int* __restrict__ pflag) {
  const int isf32 = *pflag;
  const size_t gid = (size_t)blockIdx.x * 256 + threadIdx.x;  // S*B*D/8 total
  const int d0 = (int)(gid & (DMODEL / 8 - 1)) * 8;
  const size_t sb = gid >> 7;              // s*B + b
  const size_t s = sb >> 1, b = sb & 1;
  uint4 v = ld8(x, sb * DMODEL + d0, isf32);
  *(uint4*)&xb[(b * S_LEN + s) * DMODEL + d0] = v;
}

// cvt_mat: flat convert src -> dst bf16 (8 elems/thread).
__global__ __launch_bounds__(256) void cvt_mat(const void* __restrict__ src,
                                               uint16_t* __restrict__ dst,
                                               const int* __restrict__ pflag) {
  const int isf32 = *pflag;
  const size_t gid = ((size_t)blockIdx.x * 256 + threadIdx.x) * 8;
  *(uint4*)&dst[gid] = ld8(src, gid, isf32);
}

// cvt_matT: src [R][C] (f32/bf16 row-major) -> dst [C][R] bf16 (transposed).
// One-time weight transpose so GEMM B-staging is pure vector traffic.
__global__ __launch_bounds__(256) void cvt_matT(const void* __restrict__ src,
                                                uint16_t* __restrict__ dst,
                                                int R, int C,
                                                const int* __restrict__ pflag) {
  __shared__ uint16_t lT[64 * 72];
  const int isf32 = *pflag;
  const int tid = threadIdx.x;
  const int c0 = blockIdx.x * 64;
  const int r0 = blockIdx.y * 64;
  {
    const int rr = tid >> 2, cc = (tid & 3) * 16;
    *(uint4*)&lT[rr * 72 + cc]     = ld8(src, (size_t)(r0 + rr) * C + c0 + cc, isf32);
    *(uint4*)&lT[rr * 72 + cc + 8] = ld8(src, (size_t)(r0 + rr) * C + c0 + cc + 8, isf32);
  }
  __syncthreads();
  const int oc = tid >> 2, rc = (tid & 3) * 16;
  uint16_t tmp[16];
#pragma unroll
  for (int e = 0; e < 16; e++) tmp[e] = lT[(rc + e) * 72 + oc];
  uint16_t* dp = dst + (size_t)(c0 + oc) * R + r0 + rc;
  *(uint4*)dp = *(const uint4*)&tmp[0];
  *(uint4*)(dp + 8) = *(const uint4*)&tmp[8];
}

// ---------------------------------------------------------------------------
// qkv_gemm: unified 128x128-tile GEMM for q/k/v/r production.
// grid.x = strip {0,1,2 = q,k,v ; 3 = r}; grid.y = s-block; grid.z = zpair t.
// R8: BK=64 (2 MFMA-K per stage) halves barrier/drain count (32->16 iters).
// A and B both LDS-padded to 72-elem rows (bank-rotating stride).
__global__ __launch_bounds__(256) void qkv_gemm(
    const uint16_t* __restrict__ xb, const uint16_t* __restrict__ peb,
    const uint16_t* __restrict__ wqT, const uint16_t* __restrict__ wrT,
    uint16_t* __restrict__ qb, uint16_t* __restrict__ kb,
    uint16_t* __restrict__ vb, uint16_t* __restrict__ rb, int z0) {
  __shared__ uint16_t lA[128 * 72];
  __shared__ uint16_t lB[128 * 72];
  const int tid = threadIdx.x;
  const int lane = tid & 63;
  const int wave = tid >> 6;
  const int wm = wave >> 1, wn = wave & 1;
  const int strip = blockIdx.x;
  const int zg0 = z0 + 2 * blockIdx.z;
  const int b = zg0 >> 4, h0 = zg0 & 15;

  const uint16_t* Ab;
  const uint16_t* BT;
  int col0;
  if (strip < 3) {
    Ab = xb + (size_t)b * S_LEN * DMODEL;
    BT = wqT; col0 = strip * DMODEL + h0 * 64;
  } else {
    Ab = peb;
    BT = wrT; col0 = h0 * 64;
  }
  Ab += (size_t)blockIdx.y * 128 * DMODEL;

  floatx4 acc[4][4];
  floatx4 zero4 = {0.f, 0.f, 0.f, 0.f};
#pragma unroll
  for (int i = 0; i < 4; i++)
#pragma unroll
    for (int j = 0; j < 4; j++) acc[i][j] = zero4;

  const int srow = tid >> 1;        // 0..127
  const int skc = (tid & 1) * 32;   // 0 / 32
  const int l15 = lane & 15;
  const int l4 = lane >> 4;

  for (int k0 = 0; k0 < DMODEL; k0 += 64) {
    const uint16_t* ap = Ab + (size_t)srow * DMODEL + k0 + skc;
    const uint16_t* bp = BT + (size_t)(col0 + srow) * DMODEL + k0 + skc;
#pragma unroll
    for (int e = 0; e < 4; e++) {
      *(uint4*)&lA[srow * 72 + skc + e * 8] = *(const uint4*)(ap + e * 8);
      *(uint4*)&lB[srow * 72 + skc + e * 8] = *(const uint4*)(bp + e * 8);
    }
    __syncthreads();
#pragma unroll
    for (int ks = 0; ks < 2; ks++) {
      bf16x8 af[4], bfr[4];
#pragma unroll
      for (int mi = 0; mi < 4; mi++)
        af[mi] = *(const bf16x8*)&lA[(wm * 64 + mi * 16 + l15) * 72 + ks * 32 + l4 * 8];
#pragma unroll
      for (int ni = 0; ni < 4; ni++)
        bfr[ni] = *(const bf16x8*)&lB[(wn * 64 + ni * 16 + l15) * 72 + ks * 32 + l4 * 8];
#pragma unroll
      for (int mi = 0; mi < 4; mi++)
#pragma unroll
        for (int ni = 0; ni < 4; ni++)
          acc[mi][ni] = __builtin_amdgcn_mfma_f32_16x16x32_bf16(af[mi], bfr[ni], acc[mi][ni], 0, 0, 0);
    }
    __syncthreads();
  }

  uint16_t* ob = (strip == 0) ? qb : (strip == 1) ? kb : (strip == 2) ? vb : rb;
  const int r0 = blockIdx.y * 128 + wm * 64;
  const int zlb = 2 * blockIdx.z;
#pragma unroll
  for (int mi = 0; mi < 4; mi++)
#pragma unroll
    for (int ni = 0; ni < 4; ni++)
#pragma unroll
      for (int v = 0; v < 4; v++) {
        const int sg = r0 + mi * 16 + (lane >> 4) * 4 + v;
        const int c  = wn * 64 + ni * 16 + (lane & 15);
        const int zl = zlb + (c >> 6);
        const int d  = c & 63;
        ob[(size_t)zl * HS + (size_t)sg * 64 + d] = f2bf_hw(acc[mi][ni][v]);
      }
}

// ---------------------------------------------------------------------------
// transpose_v: vb [2048][64] per z -> vt [64][2048] per z.
__global__ __launch_bounds__(256) void transpose_v(const uint16_t* __restrict__ vb,
                                                   uint16_t* __restrict__ vt) {
  __shared__ uint16_t lT[64 * 72];
  const int tid = threadIdx.x;
  const int zl = blockIdx.y;
  const int j0 = blockIdx.x * 64;
  const uint16_t* src = vb + (size_t)zl * HS + (size_t)j0 * 64;
  {
    const int j = tid >> 2, dc = (tid & 3) * 16;
    *(uint4*)&lT[j * 72 + dc] = *(const uint4*)(src + (size_t)j * 64 + dc);
    *(uint4*)&lT[j * 72 + dc + 8] = *(const uint4*)(src + (size_t)j * 64 + dc + 8);
  }
  __syncthreads();
  const int d = tid >> 2, jc = (tid & 3) * 16;
  uint16_t tmp[16];
#pragma unroll
  for (int e = 0; e < 16; e++) tmp[e] = lT[(jc + e) * 72 + d];
  uint16_t* dst = vt + (size_t)zl * HS + (size_t)d * S_LEN + j0 + jc;
  *(uint4*)dst = *(const uint4*)&tmp[0];
  *(uint4*)(dst + 8) = *(const uint4*)&tmp[8];
}

// ---------------------------------------------------------------------------
// flash_attn: fused AC + rel-shifted BD + online softmax + PV.
//
// rel-shift: D = j - i; BD[i][j] = (D<=0) ? (q_i+bv).r[D+S-1]
//                       : (D==1) ? 0 : (q_{i+1}+bv).r[D-2]
// r band STAGED in LDS (coalesced). Shear applied IN REGISTERS via lane
// rotation: src lane = l4*16 + ((l15+15-r)&15), fragment f' = f + (l15>r).
//
// 1 BLOCK/CU (launch_bounds(512,2), 107.5 KB LDS): co-resident blocks sweep
// bx in LOCKSTEP -> cache reuse works (FETCH 16.5 MB). Do not raise blk/CU.
// T14 async-STAGE via explicit register vars (R6, verified no spill).
// exp2-domain softmax (R7, kept). PBP back to 136 (R7's 132 made odd P-rows
// 8-mod-16-byte aligned -> misaligned b128 PV reads; +24 us regression).
#define FBP 72    // K-tile & r-band LDS row stride (elems)
#define VTP 136   // V^T tile LDS row stride
#define PBP 136   // softmaxed-P LDS row stride (rows 16B-aligned!)
#define SC2 0.180336880f  // 0.125 * log2(e)

#define FA_ISSUE(bxn) do {                                                  \
    const uint16_t* spk_ = kz + (size_t)((bxn) * 128 + sj) * 64 + skc;      \
    kr0 = *(const uint4*)spk_;                                              \
    kr1 = *(const uint4*)(spk_ + 8);                                        \
    const uint16_t* spv_ = vz + (size_t)sd * S_LEN + (bxn) * 128 + sjc;     \
    vr0 = *(const uint4*)spv_;                                              \
    vr1 = *(const uint4*)(spv_ + 8);                                        \
    const int Dq_ = ((bxn) - by) * 128 + sslot - 127;                       \
    int rrow_ = (Dq_ <= 0) ? (Dq_ + S_LEN - 1) : (Dq_ - 2 < 0 ? 0 : Dq_ - 2); \
    if (rrow_ > S_LEN - 1) rrow_ = S_LEN - 1;                               \
    const uint16_t* spr_ = rz + (size_t)rrow_ * 64 + shalf;                 \
    br0 = *(const uint4*)spr_;                                              \
    br1 = *(const uint4*)(spr_ + 8);                                        \
    br2 = *(const uint4*)(spr_ + 16);                                       \
    br3 = *(const uint4*)(spr_ + 24);                                       \
  } while (0)

#define FA_COMMIT() do {                                                    \
    *(uint4*)&lK[sj * FBP + skc]     = kr0;                                 \
    *(uint4*)&lK[sj * FBP + skc + 8] = kr1;                                 \
    *(uint4*)&lV[sd * VTP + sjc]     = vr0;                                 \
    *(uint4*)&lV[sd * VTP + sjc + 8] = vr1;                                 \
    uint16_t* dp_ = &lR[sslot * FBP + shalf];                               \
    *(uint4*)(dp_)      = br0;                                              \
    *(uint4*)(dp_ + 8)  = br1;                                              \
    *(uint4*)(dp_ + 16) = br2;                                              \
    *(uint4*)(dp_ + 24) = br3;                                              \
  } while (0)

__global__ __launch_bounds__(512, 2) void flash_attn(
    const uint16_t* __restrict__ qb, const uint16_t* __restrict__ kb,
    const uint16_t* __restrict__ vt, const uint16_t* __restrict__ rb,
    const void* __restrict__ bu, const void* __restrict__ bv,
    uint16_t* __restrict__ avec, int z0, int zc,
    const int* __restrict__ pflag) {
  __shared__ uint16_t lK[128 * FBP];     // K tile [128][64]
  __shared__ uint16_t lV[64 * VTP];      // V^T tile [64][128]
  __shared__ uint16_t lR[256 * FBP];     // r band [256][64]
  __shared__ uint16_t lP[8 * 16 * PBP];  // per-wave softmaxed P
  const int isf32 = *pflag;
  const int tid = threadIdx.x;
  const int lane = tid & 63;
  const int w = tid >> 6;            // wave 0..7, owns 16 output rows
  const int l15 = lane & 15;
  const int l4 = lane >> 4;
  // XCD-pinned decode (round-robin bid%8 -> XCD): all 16 by-blocks of a zl
  // land on one XCD; cohort of 256 resident blocks = 2 zl per XCD.
  int by, zl;
  {
    const int bid = blockIdx.x;
    if ((zc & 7) == 0) {
      const int xcd = bid & 7;
      const int t = bid >> 3;
      by = t & 15;
      zl = xcd + 8 * (t >> 4);
    } else {
      by = bid & 15;
      zl = bid >> 4;
    }
  }
  const int zg = z0 + zl;
  const int b = zg >> 4, h = zg & 15;
  const int i0 = by * 128;

  const uint16_t* qz = qb + (size_t)zl * HS;
  const uint16_t* kz = kb + (size_t)zl * HS;
  const uint16_t* vz = vt + (size_t)zl * HS;
  const uint16_t* rz = rb + (size_t)zl * HS;
  uint16_t* pbw = lP + w * 16 * PBP;        // wave-local P slice
  const int cmin = 112 - 16 * w;     // wave's band window start (abs band col)
  const int r_loc = l4 * 4;

  // staging thread roles (fixed per thread)
  const int sj = tid >> 2, skc = (tid & 3) * 16;      // K
  const int sd = tid >> 3, sjc = (tid & 7) * 16;      // V^T
  const int sslot = tid >> 1, shalf = (tid & 1) * 32; // band

  // staged register tiles (explicit top-level vars; no lambda captures)
  uint4 kr0, kr1, vr0, vr1, br0, br1, br2, br3;

  // Preload A fragments: af1 = q+bu (AC), af2 = q+bv, af2s = q_{row+1}+bv.
  uint4 af1[2], af2[2], af2s[2];
  {
    const int qrow = i0 + w * 16 + l15;
    const int qrow1 = min(qrow + 1, S_LEN - 1);  // clamped row never consumed
#pragma unroll
    for (int ks = 0; ks < 2; ks++) {
      const int kc = ks * 32 + l4 * 8;
      uint4 bub = ld8(bu, (size_t)h * 64 + kc, isf32);
      uint4 bvb = ld8(bv, (size_t)h * 64 + kc, isf32);
      uint4 qv  = *(const uint4*)(qz + (size_t)qrow * 64 + kc);
      uint4 qv1 = *(const uint4*)(qz + (size_t)qrow1 * 64 + kc);
      af1[ks]  = addb8(qv, bub);
      af2[ks]  = addb8(qv, bvb);
      af2s[ks] = addb8(qv1, bvb);
    }
  }

  floatx4 acc_o[4];
  floatx4 zero4 = {0.f, 0.f, 0.f, 0.f};
#pragma unroll
  for (int i = 0; i < 4; i++) acc_o[i] = zero4;
  float m[4] = {-1e30f, -1e30f, -1e30f, -1e30f};
  float l[4] = {0.f, 0.f, 0.f, 0.f};

  // prologue: stage tile 0
  FA_ISSUE(0);
  FA_COMMIT();
  __syncthreads();

  for (int bx = 0; bx < 16; ++bx) {
    const int del = bx - by;
    // T14: issue next tile's loads now; they retire under the compute below
    if (bx < 15) FA_ISSUE(bx + 1);

    // band GEMM: 9 fragments covering wave's 144-wide window (B from lR)
    floatx4 accp[9];
#pragma unroll
    for (int f = 0; f < 9; f++) accp[f] = zero4;
#pragma unroll
    for (int ks = 0; ks < 2; ks++) {
      const bf16x8 a1 = *(const bf16x8*)&af2[ks];
      const bf16x8 a2 = *(const bf16x8*)&af2s[ks];
#pragma unroll
      for (int f = 0; f < 9; f++) {
        const int cb = cmin + 16 * f;
        const bf16x8 brg = *(const bf16x8*)&lR[(cb + l15) * FBP + ks * 32 + l4 * 8];
        const bf16x8 a = (cb >= 128 - 128 * del) ? a2 : a1;  // wave-uniform
        accp[f] = __builtin_amdgcn_mfma_f32_16x16x32_bf16(a, brg, accp[f], 0, 0, 0);
      }
    }
    // AC GEMM: S_ac[16 rows][128 cols] per wave
    floatx4 acc_s[8];
#pragma unroll
    for (int f = 0; f < 8; f++) acc_s[f] = zero4;
#pragma unroll
    for (int ks = 0; ks < 2; ks++) {
      const bf16x8 a = *(const bf16x8*)&af1[ks];
#pragma unroll
      for (int f = 0; f < 8; f++) {
        const bf16x8 bk = *(const bf16x8*)&lK[(f * 16 + l15) * FBP + ks * 32 + l4 * 8];
        acc_s[f] = __builtin_amdgcn_mfma_f32_16x16x32_bf16(a, bk, acc_s[f], 0, 0, 0);
      }
    }

    // in-register shear + combine + scale (exp2 domain) + rowmax
    float rmax[4] = {-1e30f, -1e30f, -1e30f, -1e30f};
#pragma unroll
    for (int v = 0; v < 4; v++) {
      const int r = r_loc + v;
      const int srcl = l4 * 16 + ((l15 + 15 - r) & 15);
      float sh[9];
#pragma unroll
      for (int f = 0; f < 9; f++) sh[f] = __shfl(accp[f][v], srcl);
      const int Dbase = del * 128 + l15 - w * 16 - r;  // D = Dbase + 16f
#pragma unroll
      for (int f = 0; f < 8; f++) {
        float bd = (l15 <= r) ? sh[f] : sh[f + 1];
        if (Dbase + 16 * f == 1) bd = 0.f;
        const float sv = (acc_s[f][v] + bd) * SC2;   // log2-domain score
        acc_s[f][v] = sv;
        rmax[v] = fmaxf(rmax[v], sv);
      }
    }
    // online softmax (all exps are 2^x -> single v_exp_f32)
#pragma unroll
    for (int v = 0; v < 4; v++) {
#pragma unroll
      for (int o = 1; o < 16; o <<= 1) rmax[v] = fmaxf(rmax[v], __shfl_xor(rmax[v], o));
      const float mn = fmaxf(m[v], rmax[v]);
      const float al = __builtin_amdgcn_exp2f(m[v] - mn);
      m[v] = mn;
      l[v] *= al;
#pragma unroll
      for (int nd = 0; nd < 4; nd++) acc_o[nd][v] *= al;
    }
    float rsum[4] = {0.f, 0.f, 0.f, 0.f};
#pragma unroll
    for (int f = 0; f < 8; f++)
#pragma unroll
      for (int v = 0; v < 4; v++) {
        const float p = __builtin_amdgcn_exp2f(acc_s[f][v] - m[v]);
        acc_s[f][v] = p;
        rsum[v] += p;
      }
#pragma unroll
    for (int v = 0; v < 4; v++) {
#pragma unroll
      for (int o = 1; o < 16; o <<= 1) rsum[v] += __shfl_xor(rsum[v], o);
      l[v] += rsum[v];
    }
    // write softmaxed P [16][128] into wave-local lP (separate buffer ->
    // no cross-wave hazard, no barrier)
#pragma unroll
    for (int f = 0; f < 8; f++)
#pragma unroll
      for (int v = 0; v < 4; v++)
        pbw[(r_loc + v) * PBP + f * 16 + l15] = f2bf_hw(acc_s[f][v]);

    // PV GEMM: acc_o += P(16x128) . V(128x64)
#pragma unroll
    for (int ks = 0; ks < 4; ks++) {
      const bf16x8 ap = *(const bf16x8*)&pbw[l15 * PBP + ks * 32 + l4 * 8];
#pragma unroll
      for (int nd = 0; nd < 4; nd++) {
        const bf16x8 bvv = *(const bf16x8*)&lV[(nd * 16 + l15) * VTP + ks * 32 + l4 * 8];
        acc_o[nd] = __builtin_amdgcn_mfma_f32_16x16x32_bf16(ap, bvv, acc_o[nd], 0, 0, 0);
      }
    }

    __syncthreads();  // (A) all waves' lK/lV/lR reads of tile bx done
    if (bx < 15) {
      FA_COMMIT();     // staged regs -> LDS (loads already retired)
      __syncthreads(); // (B) tile bx+1 visible
    }
  }

  // epilogue: normalize by row sum, write avec
#pragma unroll
  for (int v = 0; v < 4; v++) {
    const float inv = 1.f / l[v];
    const int i = i0 + w * 16 + r_loc + v;
#pragma unroll
    for (int nd = 0; nd < 4; nd++) {
      const int d = nd * 16 + l15;
      avec[((size_t)i * BATCH + b) * DMODEL + h * 64 + d] = f2bf_hw(acc_o[nd][v] * inv);
    }
  }
}

// ---------------------------------------------------------------------------
// out_gemm: ybuf = avec (4096x1024) @ Wo (via pre-transposed woT [n][k]) + x.
// R8: BK=64 (same transformation as qkv_gemm).
__global__ __launch_bounds__(256) void out_gemm(
    const uint16_t* __restrict__ avec, const uint16_t* __restrict__ woT,
    const void* __restrict__ x, uint16_t* __restrict__ ybuf,
    const int* __restrict__ pflag) {
  __shared__ uint16_t lA[128 * 72];
  __shared__ uint16_t lB[128 * 72];
  const int isf32 = *pflag;
  const int tid = threadIdx.x;
  const int lane = tid & 63;
  const int wave = tid >> 6;
  const int wm = wave >> 1, wn = wave & 1;
  const uint16_t* Ab = avec + (size_t)blockIdx.y * 128 * DMODEL;
  const int col0 = blockIdx.x * 128;

  floatx4 acc[4][4];
  floatx4 zero4 = {0.f, 0.f, 0.f, 0.f};
#pragma unroll
  for (int i = 0; i < 4; i++)
#pragma unroll
    for (int j = 0; j < 4; j++) acc[i][j] = zero4;

  const int srow = tid >> 1;        // 0..127
  const int skc = (tid & 1) * 32;   // 0 / 32
  const int l15 = lane & 15;
  const int l4 = lane >> 4;

  for (int k0 = 0; k0 < DMODEL; k0 += 64) {
    const uint16_t* ap = Ab + (size_t)srow * DMODEL + k0 + skc;
    const uint16_t* bp = woT + (size_t)(col0 + srow) * DMODEL + k0 + skc;
#pragma unroll
    for (int e = 0; e < 4; e++) {
      *(uint4*)&lA[srow * 72 + skc + e * 8] = *(const uint4*)(ap + e * 8);
      *(uint4*)&lB[srow * 72 + skc + e * 8] = *(const uint4*)(bp + e * 8);
    }
    __syncthreads();
#pragma unroll
    for (int ks = 0; ks < 2; ks++) {
      bf16x8 af[4], bfr[4];
#pragma unroll
      for (int mi = 0; mi < 4; mi++)
        af[mi] = *(const bf16x8*)&lA[(wm * 64 + mi * 16 + l15) * 72 + ks * 32 + l4 * 8];
#pragma unroll
      for (int ni = 0; ni < 4; ni++)
        bfr[ni] = *(const bf16x8*)&lB[(wn * 64 + ni * 16 + l15) * 72 + ks * 32 + l4 * 8];
#pragma unroll
      for (int mi = 0; mi < 4; mi++)
#pragma unroll
        for (int ni = 0; ni < 4; ni++)
          acc[mi][ni] = __builtin_amdgcn_mfma_f32_16x16x32_bf16(af[mi], bfr[ni], acc[mi][ni], 0, 0, 0);
    }
    __syncthreads();
  }

  const int r0 = blockIdx.y * 128 + wm * 64;
#pragma unroll
  for (int mi = 0; mi < 4; mi++)
#pragma unroll
    for (int ni = 0; ni < 4; ni++)
#pragma unroll
      for (int v = 0; v < 4; v++) {
        const int rg = r0 + mi * 16 + (lane >> 4) * 4 + v;
        const int cg = col0 + wn * 64 + ni * 16 + (lane & 15);
        const size_t o = (size_t)rg * DMODEL + cg;
        ybuf[o] = f2bf_hw(acc[mi][ni][v] + ld1(x, o, isf32));
      }
}

// ---------------------------------------------------------------------------
// LayerNorm over D=1024, bf16 in (ybuf), FLOAT32 out (reference output dtype).
__global__ __launch_bounds__(256) void ln_f32(
    const uint16_t* __restrict__ y, const void* __restrict__ gamma,
    const void* __restrict__ beta, float* __restrict__ out,
    const int* __restrict__ pflag) {
  const int isf32 = *pflag;
  const int row = blockIdx.x;
  const int tid = threadIdx.x;
  const int lane = tid & 63, wave = tid >> 6;
  const uint16_t* yr = y + (size_t)row * DMODEL;
  uint2 u = *(const uint2*)(yr + tid * 4);
  const uint16_t* up = (const uint16_t*)&u;
  float f[4];
  float s = 0.f, q = 0.f;
#pragma unroll
  for (int j = 0; j < 4; j++) { f[j] = bf2f(up[j]); s += f[j]; q += f[j] * f[j]; }
#pragma unroll
  for (int o = 32; o; o >>= 1) { s += __shfl_xor(s, o); q += __shfl_xor(q, o); }
  __shared__ float rs[4], rq[4];
  if (lane == 0) { rs[wave] = s; rq[wave] = q; }
  __syncthreads();
  s = rs[0] + rs[1] + rs[2] + rs[3];
  q = rq[0] + rq[1] + rq[2] + rq[3];
  const float mu = s * (1.f / DMODEL);
  const float var = fmaxf(q * (1.f / DMODEL) - mu * mu, 0.f);
  const float inv = rsqrtf(var + 1e-5f);
  float4 o4;
  float* op = (float*)&o4;
#pragma unroll
  for (int j = 0; j < 4; j++) {
    const int c = tid * 4 + j;
    float r = (f[j] - mu) * inv * ld1(gamma, c, isf32) + ld1(beta, c, isf32);
    if (!(r == r)) r = 1e4f;  // diagnostic sentinel: NaN reached LN
    op[j] = r;
  }
  *(float4*)(out + (size_t)row * DMODEL + tid * 4) = o4;
}

// Sentinel: ws too small — fill output with 1e6 so absmax reports it.
__global__ __launch_bounds__(256) void sentinel_fill(float* __restrict__ out) {
  const size_t i = (size_t)blockIdx.x * 1024 + threadIdx.x * 4;
  out[i] = 1e6f; out[i + 1] = 1e6f; out[i + 2] = 1e6f; out[i + 3] = 1e6f;
}

extern "C" void kernel_launch(void* const* d_in, const int* in_sizes, int n_in,
                              void* d_out, int out_size, void* d_ws, size_t ws_size,
                              hipStream_t stream) {
  const void* x    = d_in[0];
  const void* pe   = d_in[1];
  const void* bu   = d_in[2];
  const void* bv   = d_in[3];
  const void* Wqkv = d_in[4];
  const void* Wrel = d_in[5];
  const void* Wo   = d_in[6];
  const void* gam  = d_in[7];
  const void* bet  = d_in[8];
  float* out = (float*)d_out;

  // Layout: [flag 256B][qb|kb|vb|rb|vt: 5*ZC*256KB]
  //         [conv: xb 8M | peb 4M | wqT 6M | wrT 2M | woT 2M]
  // ybuf (8 MB) reuses xb after attention completes.
  const size_t per_z = 5 * HS * 2;                                   // 1.25 MB
  const size_t conv_bytes = (size_t)(8 + 4 + 6 + 2 + 2) * 1024 * 1024;
  int ZC = 0;
  for (int c = 32; c >= 2; c >>= 1)
    if (256 + (size_t)c * per_z + conv_bytes <= ws_size) { ZC = c; break; }

  const dim3 blk(256);
  if (ZC == 0) {
    sentinel_fill<<<dim3(4096), blk, 0, stream>>>(out);
    return;
  }

  int* flag = (int*)d_ws;
  uint16_t* qb  = (uint16_t*)((char*)d_ws + 256);
  uint16_t* kb  = qb + (size_t)ZC * HS;
  uint16_t* vb  = kb + (size_t)ZC * HS;
  uint16_t* rb  = vb + (size_t)ZC * HS;
  uint16_t* vtb = rb + (size_t)ZC * HS;
  uint16_t* xbuf = vtb + (size_t)ZC * HS;              // conv region start
  uint16_t* peb  = xbuf + (size_t)BATCH * S_LEN * DMODEL;
  uint16_t* wqT  = peb + (size_t)S_LEN * DMODEL;
  uint16_t* wrT  = wqT + (size_t)DMODEL * 3 * DMODEL;
  uint16_t* woT  = wrT + (size_t)DMODEL * DMODEL;
  uint16_t* ybuf = xbuf;              // reused after attention completes
  uint16_t* avec = (uint16_t*)d_out;  // d_out (16 MB) first 8 MB as bf16 scratch

  detect_dtype<<<dim3(1), blk, 0, stream>>>(x, flag);
  cvt_x<<<dim3(2048), blk, 0, stream>>>(x, xbuf, flag);
  cvt_mat<<<dim3(1024), blk, 0, stream>>>(pe, peb, flag);              // 2048x1024
  cvt_matT<<<dim3(48, 16), blk, 0, stream>>>(Wqkv, wqT, DMODEL, 3 * DMODEL, flag);
  cvt_matT<<<dim3(16, 16), blk, 0, stream>>>(Wrel, wrT, DMODEL, DMODEL, flag);
  cvt_matT<<<dim3(16, 16), blk, 0, stream>>>(Wo,   woT, DMODEL, DMODEL, flag);

  for (int z0 = 0; z0 < 32; z0 += ZC) {
    qkv_gemm<<<dim3(4, 16, ZC / 2), blk, 0, stream>>>(xbuf, peb, wqT, wrT,
                                                      qb, kb, vb, rb, z0);
    transpose_v<<<dim3(32, ZC), blk, 0, stream>>>(vb, vtb);
    flash_attn<<<dim3(16 * ZC), dim3(512), 0, stream>>>(qb, kb, vtb, rb, bu, bv,
                                                        avec, z0, ZC, flag);
  }

  out_gemm<<<dim3(8, 32, 1), blk, 0, stream>>>(avec, woT, x, ybuf, flag);
  ln_f32<<<dim3(4096), blk, 0, stream>>>(ybuf, gam, bet, out, flag);
}